// Round 1
// baseline (632.714 us; speedup 1.0000x reference)
//
#include <hip/hip_runtime.h>
#include <cstddef>

// HyenaCascade: depthwise causal conv (K=3) -> 8-pole diagonal SSM scan
// (exact replacement for the reference's FFT long-conv) -> gated output.
//
// Constants from the reference:
namespace {
constexpr int kB   = 2;
constexpr int kL   = 8192;
constexpr int kHid = 2048;   // HIDDEN == GROUPS
constexpr int kC3  = 6144;   // 3*HIDDEN
constexpr int kS   = 8;      // state size
constexpr int kNC  = 64;     // number of sequence chunks
constexpr int kCL  = kL / kNC; // 128 steps per chunk
} // namespace

// Pass 1: per (b, chunk, channel d) compute x1v = x1*v from u via the K=3
// depthwise conv, run the local scan from zero state, store the chunk-end
// state A[b][chunk][d][s]  (8 floats per channel-chunk).
__global__ __launch_bounds__(256) void hyena_pass1(
    const float* __restrict__ u, const float* __restrict__ w,
    const float* __restrict__ bias, const float* __restrict__ lp,
    float* __restrict__ A)
{
  const int d  = blockIdx.x * 256 + threadIdx.x;   // 0..2047
  const int ch = blockIdx.y;                        // chunk
  const int b  = blockIdx.z;
  const int head = d >> 7, r = d & 127;
  const int c1 = head * 384 + 128 + r;              // x1 channel in z_pre
  const int cv = head * 384 + 256 + r;              // v channel

  const float w10 = w[c1*3+0], w11 = w[c1*3+1], w12 = w[c1*3+2], b1 = bias[c1];
  const float wv0 = w[cv*3+0], wv1 = w[cv*3+1], wv2 = w[cv*3+2], bv = bias[cv];

  float p[kS];
  #pragma unroll
  for (int j = 0; j < kS; ++j) p[j] = expf(lp[d*kS + j]);

  const int l0 = ch * kCL;
  const float* ub = u + (size_t)b * kL * kC3;

  float u1m2 = 0.f, u1m1 = 0.f, uvm2 = 0.f, uvm1 = 0.f;
  if (l0 >= 2) { u1m2 = ub[(size_t)(l0-2)*kC3 + c1]; uvm2 = ub[(size_t)(l0-2)*kC3 + cv]; }
  if (l0 >= 1) { u1m1 = ub[(size_t)(l0-1)*kC3 + c1]; uvm1 = ub[(size_t)(l0-1)*kC3 + cv]; }

  float s[kS];
  #pragma unroll
  for (int j = 0; j < kS; ++j) s[j] = 0.f;

  #pragma unroll 4
  for (int l = l0; l < l0 + kCL; ++l) {
    const float u1 = ub[(size_t)l*kC3 + c1];
    const float uv = ub[(size_t)l*kC3 + cv];
    const float x1 = fmaf(w10, u1m2, fmaf(w11, u1m1, fmaf(w12, u1, b1)));
    const float v  = fmaf(wv0, uvm2, fmaf(wv1, uvm1, fmaf(wv2, uv, bv)));
    const float x  = x1 * v;
    #pragma unroll
    for (int j = 0; j < kS; ++j) s[j] = fmaf(p[j], s[j], x);
    u1m2 = u1m1; u1m1 = u1; uvm2 = uvm1; uvm1 = uv;
  }

  float* Ad = A + (((size_t)b*kNC + ch)*kHid + d) * kS;
  #pragma unroll
  for (int j = 0; j < kS; ++j) Ad[j] = s[j];
}

// Pass 2: in-place inclusive combine across chunks:
//   S[c] = p^CL * S[c-1] + A[c]   (per (b,d,s) line; lines are disjoint)
__global__ __launch_bounds__(256) void hyena_pass2(
    const float* __restrict__ lp, float* __restrict__ A)
{
  const int t = blockIdx.x * 256 + threadIdx.x;    // over B*HID*S = 32768
  const int j = t & (kS - 1);
  const int d = (t >> 3) & (kHid - 1);
  const int b = t >> 14;
  const float pC = expf(lp[d*kS + j] * (float)kCL);

  const size_t base   = (size_t)b * kNC * kHid * kS + (size_t)d * kS + j;
  const size_t stride = (size_t)kHid * kS;

  float s = 0.f;
  for (int c0 = 0; c0 < kNC; c0 += 8) {
    float a[8];
    #pragma unroll
    for (int k = 0; k < 8; ++k) a[k] = A[base + (size_t)(c0 + k) * stride];
    #pragma unroll
    for (int k = 0; k < 8; ++k) {
      s = fmaf(pC, s, a[k]);
      A[base + (size_t)(c0 + k) * stride] = s;
    }
  }
}

// Pass 3: re-derive x1v and x2 from u, scan with the combined incoming state
// (end-state of chunk-1), emit out[b][l][d] = (y + x1v*D) * x2.
__global__ __launch_bounds__(256) void hyena_pass3(
    const float* __restrict__ u, const float* __restrict__ w,
    const float* __restrict__ bias, const float* __restrict__ lp,
    const float* __restrict__ res, const float* __restrict__ Dv,
    const float* __restrict__ A, float* __restrict__ out)
{
  const int d  = blockIdx.x * 256 + threadIdx.x;
  const int ch = blockIdx.y;
  const int b  = blockIdx.z;
  const int head = d >> 7, r = d & 127;
  const int c2 = head * 384 + r;        // x2 channel
  const int c1 = c2 + 128;              // x1 channel
  const int cv = c2 + 256;              // v channel

  const float w20 = w[c2*3+0], w21 = w[c2*3+1], w22 = w[c2*3+2], b2 = bias[c2];
  const float w10 = w[c1*3+0], w11 = w[c1*3+1], w12 = w[c1*3+2], b1 = bias[c1];
  const float wv0 = w[cv*3+0], wv1 = w[cv*3+1], wv2 = w[cv*3+2], bv = bias[cv];
  const float Dd = Dv[d];

  float p[kS], rr[kS], s[kS];
  #pragma unroll
  for (int j = 0; j < kS; ++j) {
    p[j]  = expf(lp[d*kS + j]);
    rr[j] = res[d*kS + j];
  }
  if (ch == 0) {
    #pragma unroll
    for (int j = 0; j < kS; ++j) s[j] = 0.f;
  } else {
    const float* Ad = A + (((size_t)b*kNC + (ch - 1))*kHid + d) * kS;
    #pragma unroll
    for (int j = 0; j < kS; ++j) s[j] = Ad[j];
  }

  const int l0 = ch * kCL;
  const float* ub = u + (size_t)b * kL * kC3;

  float u2m2 = 0.f, u2m1 = 0.f, u1m2 = 0.f, u1m1 = 0.f, uvm2 = 0.f, uvm1 = 0.f;
  if (l0 >= 2) {
    u2m2 = ub[(size_t)(l0-2)*kC3 + c2];
    u1m2 = ub[(size_t)(l0-2)*kC3 + c1];
    uvm2 = ub[(size_t)(l0-2)*kC3 + cv];
  }
  if (l0 >= 1) {
    u2m1 = ub[(size_t)(l0-1)*kC3 + c2];
    u1m1 = ub[(size_t)(l0-1)*kC3 + c1];
    uvm1 = ub[(size_t)(l0-1)*kC3 + cv];
  }

  float* ob = out + (size_t)b * kL * kHid + d;

  #pragma unroll 4
  for (int l = l0; l < l0 + kCL; ++l) {
    const float u2 = ub[(size_t)l*kC3 + c2];
    const float u1 = ub[(size_t)l*kC3 + c1];
    const float uv = ub[(size_t)l*kC3 + cv];
    const float x2 = fmaf(w20, u2m2, fmaf(w21, u2m1, fmaf(w22, u2, b2)));
    const float x1 = fmaf(w10, u1m2, fmaf(w11, u1m1, fmaf(w12, u1, b1)));
    const float v  = fmaf(wv0, uvm2, fmaf(wv1, uvm1, fmaf(wv2, uv, bv)));
    const float x  = x1 * v;
    #pragma unroll
    for (int j = 0; j < kS; ++j) s[j] = fmaf(p[j], s[j], x);
    float y = 0.f;
    #pragma unroll
    for (int j = 0; j < kS; ++j) y = fmaf(rr[j], s[j], y);
    ob[(size_t)l * kHid] = fmaf(x, Dd, y) * x2;
    u2m2 = u2m1; u2m1 = u2; u1m2 = u1m1; u1m1 = u1; uvm2 = uvm1; uvm1 = uv;
  }
}

extern "C" void kernel_launch(void* const* d_in, const int* in_sizes, int n_in,
                              void* d_out, int out_size, void* d_ws, size_t ws_size,
                              hipStream_t stream) {
  const float* u    = (const float*)d_in[0];  // [B, L, 3*HID] fp32
  const float* w    = (const float*)d_in[1];  // [3*HID, 1, 3]
  const float* bias = (const float*)d_in[2];  // [3*HID]
  const float* lp   = (const float*)d_in[3];  // [HID, S, 1]
  const float* res  = (const float*)d_in[4];  // [HID, S]
  const float* Dv   = (const float*)d_in[5];  // [HID]
  float* out = (float*)d_out;                 // [B, L, HID]
  float* A   = (float*)d_ws;                  // [B, NC, HID, S] = 8 MB

  const dim3 blk(256);
  const dim3 g13(kHid / 256, kNC, kB);
  hipLaunchKernelGGL(hyena_pass1, g13, blk, 0, stream, u, w, bias, lp, A);
  hipLaunchKernelGGL(hyena_pass2, dim3((kB * kHid * kS) / 256), blk, 0, stream, lp, A);
  hipLaunchKernelGGL(hyena_pass3, g13, blk, 0, stream, u, w, bias, lp, res, Dv, A, out);
}